// Round 2
// baseline (197.428 us; speedup 1.0000x reference)
//
#include <hip/hip_runtime.h>

#define N_NODES 256
#define F_DIM   16
#define H_DIM   2048
#define P_DIM   16
#define E_EDGES 32768

// K1: zero A (256x256) and set deg[i] = 1.0 (self-loop contribution)
__global__ void k_init(float* __restrict__ A, float* __restrict__ deg) {
    int t = blockIdx.x * 256 + threadIdx.x;
    A[t] = 0.0f;                 // grid exactly covers 65536
    if (t < N_NODES) deg[t] = 1.0f;
}

// K2: blocks [0,128): deg atomics over dst; blocks [128,2176): h = x @ W
__global__ void k_deg_h(const int* __restrict__ ei, float* __restrict__ deg,
                        const float* __restrict__ x,
                        const float* __restrict__ W,
                        float* __restrict__ h) {
    int b = blockIdx.x;
    if (b < 128) {
        int e = b * 256 + threadIdx.x;          // e < 32768 always
        int d = ei[E_EDGES + e];                // edge_index[1][e]
        atomicAdd(&deg[d], 1.0f);
    } else {
        int j = (b - 128) * 256 + threadIdx.x;  // j < 256*2048
        int n = j >> 11;
        int c = j & (H_DIM - 1);
        float acc = 0.0f;
#pragma unroll
        for (int f = 0; f < F_DIM; ++f)
            acc += x[n * F_DIM + f] * W[f * H_DIM + c];
        h[j] = acc;
    }
}

// K3: A[d][s] += dinv[s]*dinv[d] per edge; diagonal self-loops += 1/deg[i]
__global__ void k_A(const int* __restrict__ ei, const float* __restrict__ deg,
                    float* __restrict__ A) {
    int t = blockIdx.x * 256 + threadIdx.x;
    if (t < E_EDGES) {
        int s = ei[t];
        int d = ei[E_EDGES + t];
        float norm = rsqrtf(deg[s] * deg[d]);   // dinv[s]*dinv[d]
        atomicAdd(&A[d * N_NODES + s], norm);
    } else if (t < E_EDGES + N_NODES) {
        int i = t - E_EDGES;
        atomicAdd(&A[i * N_NODES + i], 1.0f / deg[i]);  // dinv[i]^2
    }
}

// K4: out = A @ h + b   (64 blocks: 8 node-chunks x 8 col-slabs)
__global__ void k_out(const float* __restrict__ A, const float* __restrict__ h,
                      const float* __restrict__ b,
                      float* __restrict__ out) {
    __shared__ float As[32 * 256];
    int dchunk = blockIdx.x >> 3;
    int cslab  = blockIdx.x & 7;
    int tid = threadIdx.x;
    int c = cslab * 256 + tid;
#pragma unroll
    for (int i = 0; i < 32; ++i)
        As[i * 256 + tid] = A[(dchunk * 32 + i) * N_NODES + tid];
    __syncthreads();
    float acc[32];
#pragma unroll
    for (int i = 0; i < 32; ++i) acc[i] = 0.0f;
    for (int s = 0; s < N_NODES; ++s) {
        float hv = h[s * H_DIM + c];
#pragma unroll
        for (int i = 0; i < 32; ++i) acc[i] += As[i * 256 + s] * hv;
    }
    float bc = b[c];
#pragma unroll
    for (int i = 0; i < 32; ++i)
        out[(dchunk * 32 + i) * H_DIM + c] = acc[i] + bc;
}

// K5: q[n][p] = sum_h out[n][h] * Wq[n][h][p] + bq[n][p]; one block per node
__global__ void k_q(const float* __restrict__ out,
                    const float* __restrict__ Wq,
                    const float* __restrict__ bq,
                    float* __restrict__ qout) {
    int n = blockIdx.x;
    int tid = threadIdx.x;
    float acc[16];
#pragma unroll
    for (int p = 0; p < 16; ++p) acc[p] = 0.0f;

    const float4* Wqn = (const float4*)(Wq + (size_t)n * H_DIM * P_DIM);
    for (int hh = tid; hh < H_DIM; hh += 256) {
        float o = out[n * H_DIM + hh];
        float4 u0 = Wqn[hh * 4 + 0];
        float4 u1 = Wqn[hh * 4 + 1];
        float4 u2 = Wqn[hh * 4 + 2];
        float4 u3 = Wqn[hh * 4 + 3];
        acc[0]  += o * u0.x; acc[1]  += o * u0.y; acc[2]  += o * u0.z; acc[3]  += o * u0.w;
        acc[4]  += o * u1.x; acc[5]  += o * u1.y; acc[6]  += o * u1.z; acc[7]  += o * u1.w;
        acc[8]  += o * u2.x; acc[9]  += o * u2.y; acc[10] += o * u2.z; acc[11] += o * u2.w;
        acc[12] += o * u3.x; acc[13] += o * u3.y; acc[14] += o * u3.z; acc[15] += o * u3.w;
    }

    // wave-level butterfly reduce (wave = 64)
#pragma unroll
    for (int p = 0; p < 16; ++p)
#pragma unroll
        for (int off = 32; off > 0; off >>= 1)
            acc[p] += __shfl_down(acc[p], off, 64);

    __shared__ float red[4][16];
    int wave = tid >> 6;
    int lane = tid & 63;
    if (lane == 0) {
#pragma unroll
        for (int p = 0; p < 16; ++p) red[wave][p] = acc[p];
    }
    __syncthreads();
    if (tid < 16) {
        float s = red[0][tid] + red[1][tid] + red[2][tid] + red[3][tid] +
                  bq[n * P_DIM + tid];
        qout[n * P_DIM + tid] = s;
    }
}

extern "C" void kernel_launch(void* const* d_in, const int* in_sizes, int n_in,
                              void* d_out, int out_size, void* d_ws, size_t ws_size,
                              hipStream_t stream) {
    const float* x  = (const float*)d_in[0];  // [256,16]
    const int*   ei = (const int*)d_in[1];    // [2,32768]
    const float* W  = (const float*)d_in[2];  // [16,2048]
    const float* b  = (const float*)d_in[3];  // [2048]
    const float* Wq = (const float*)d_in[4];  // [256,2048,16]
    const float* bq = (const float*)d_in[5];  // [256,16]
    float* qout = (float*)d_out;              // [256,16]

    float* ws  = (float*)d_ws;
    float* A   = ws;                     // 65536 floats (256 KB)
    float* deg = ws + 65536;             // 256 floats
    float* h   = ws + 65792;             // 524288 floats (2 MB)
    float* out = ws + 65792 + 524288;    // 524288 floats (2 MB)

    k_init <<<256,  256, 0, stream>>>(A, deg);
    k_deg_h<<<2176, 256, 0, stream>>>(ei, deg, x, W, h);
    k_A    <<<129,  256, 0, stream>>>(ei, deg, A);
    k_out  <<<64,   256, 0, stream>>>(A, h, b, out);
    k_q    <<<256,  256, 0, stream>>>(out, Wq, bq, qout);
}

// Round 3
// 120.899 us; speedup vs baseline: 1.6330x; 1.6330x over previous
//
#include <hip/hip_runtime.h>

#define N_NODES 256
#define F_DIM   16
#define H_DIM   2048
#define P_DIM   16
#define E_EDGES 32768

// ---------------------------------------------------------------------------
// ws layout (floats): cntT[65536] (cntT[s*256+d]), h[524288], out[524288]
// ---------------------------------------------------------------------------

// K1: blocks [0,128): cntT[s][d] += 1 per edge (65536 addrs, low contention)
//     blocks [128,2176): h = x @ W
__global__ void k_edges_h(const int* __restrict__ ei, float* __restrict__ cntT,
                          const float* __restrict__ x, const float* __restrict__ W,
                          float* __restrict__ h) {
    int b = blockIdx.x, t = threadIdx.x;
    if (b < 128) {
        int e = b * 256 + t;                       // e < 32768
        int s = ei[e];
        int d = ei[E_EDGES + e];
        atomicAdd(&cntT[s * N_NODES + d], 1.0f);
    } else {
        int j = (b - 128) * 256 + t;               // j < 256*2048
        int n = j >> 11;
        int c = j & (H_DIM - 1);
        float acc = 0.0f;
#pragma unroll
        for (int f = 0; f < F_DIM; ++f)
            acc += x[n * F_DIM + f] * W[f * H_DIM + c];
        h[j] = acc;
    }
}

// K2: out[d][c] = sum_s cntT[s][d]*dinv[s]*dinv[d]*h[s][c]
//               + dinv[d]^2 * h[d][c] + b[c]
// grid (16 cslabs, 16 dchunks), 256 threads; tile 16 rows x 128 cols;
// thread = 2 rows x 4 cols.  dinv recomputed per block from cntT colsums.
__global__ void k_out(const float* __restrict__ cntT, const float* __restrict__ h,
                      const float* __restrict__ bias, float* __restrict__ out) {
    __shared__ float part[4][256];
    __shared__ float dinv[256];
    int t = threadIdx.x;
    int w = t >> 6, l = t & 63;

    // phase 1: deg[d] = 1 + sum_s cntT[s][d]; each wave sums 64 s-rows,
    // lane l owns cols 4l..4l+3 (fully coalesced 1KB/wave loads)
    {
        const float4* cT4 = (const float4*)cntT;   // row s = 64 float4
        float4 sum = {0.f, 0.f, 0.f, 0.f};
        int s0 = w * 64;
#pragma unroll 8
        for (int s = s0; s < s0 + 64; ++s) {
            float4 v = cT4[s * 64 + l];
            sum.x += v.x; sum.y += v.y; sum.z += v.z; sum.w += v.w;
        }
        *(float4*)&part[w][4 * l] = sum;
    }
    __syncthreads();
    if (t < 64) {
        float4 a0 = *(float4*)&part[0][4 * t];
        float4 a1 = *(float4*)&part[1][4 * t];
        float4 a2 = *(float4*)&part[2][4 * t];
        float4 a3 = *(float4*)&part[3][4 * t];
        dinv[4 * t + 0] = rsqrtf(a0.x + a1.x + a2.x + a3.x + 1.0f);
        dinv[4 * t + 1] = rsqrtf(a0.y + a1.y + a2.y + a3.y + 1.0f);
        dinv[4 * t + 2] = rsqrtf(a0.z + a1.z + a2.z + a3.z + 1.0f);
        dinv[4 * t + 3] = rsqrtf(a0.w + a1.w + a2.w + a3.w + 1.0f);
    }
    __syncthreads();

    // phase 2: register-tiled GEMM, K unroll 8 with batched loads
    int ct = t & 31;                 // col-thread: 4 cols
    int rt = t >> 5;                 // row-thread: 2 rows
    int c = blockIdx.x * 128 + ct * 4;
    int r = blockIdx.y * 16 + rt * 2;
    float dd0 = dinv[r], dd1 = dinv[r + 1];
    float4 acc0 = {0.f, 0.f, 0.f, 0.f};
    float4 acc1 = {0.f, 0.f, 0.f, 0.f};

    for (int s0 = 0; s0 < N_NODES; s0 += 8) {
        float4 hv[8];
        float2 av[8];
#pragma unroll
        for (int u = 0; u < 8; ++u)
            hv[u] = *(const float4*)&h[(s0 + u) * H_DIM + c];
#pragma unroll
        for (int u = 0; u < 8; ++u)
            av[u] = *(const float2*)&cntT[(s0 + u) * N_NODES + r];
#pragma unroll
        for (int u = 0; u < 8; ++u) {
            float ds = dinv[s0 + u];
            float a0 = av[u].x * ds * dd0;
            float a1 = av[u].y * ds * dd1;
            acc0.x += a0 * hv[u].x; acc0.y += a0 * hv[u].y;
            acc0.z += a0 * hv[u].z; acc0.w += a0 * hv[u].w;
            acc1.x += a1 * hv[u].x; acc1.y += a1 * hv[u].y;
            acc1.z += a1 * hv[u].z; acc1.w += a1 * hv[u].w;
        }
    }

    // self-loop term + bias, store
    float4 hs0 = *(const float4*)&h[r * H_DIM + c];
    float4 hs1 = *(const float4*)&h[(r + 1) * H_DIM + c];
    float q0 = dd0 * dd0, q1 = dd1 * dd1;
    float4 bv = *(const float4*)&bias[c];
    acc0.x += q0 * hs0.x + bv.x; acc0.y += q0 * hs0.y + bv.y;
    acc0.z += q0 * hs0.z + bv.z; acc0.w += q0 * hs0.w + bv.w;
    acc1.x += q1 * hs1.x + bv.x; acc1.y += q1 * hs1.y + bv.y;
    acc1.z += q1 * hs1.z + bv.z; acc1.w += q1 * hs1.w + bv.w;
    *(float4*)&out[r * H_DIM + c] = acc0;
    *(float4*)&out[(r + 1) * H_DIM + c] = acc1;
}

// K3: q[n][p] = sum_h out[n][h]*Wq[n][h][p] + bq[n][p]; one block per node
__global__ void k_q(const float* __restrict__ out, const float* __restrict__ Wq,
                    const float* __restrict__ bq, float* __restrict__ qout) {
    int n = blockIdx.x;
    int tid = threadIdx.x;
    float acc[16];
#pragma unroll
    for (int p = 0; p < 16; ++p) acc[p] = 0.0f;

    const float4* Wqn = (const float4*)(Wq + (size_t)n * H_DIM * P_DIM);
    for (int hh = tid; hh < H_DIM; hh += 256) {
        float o = out[n * H_DIM + hh];
        float4 u0 = Wqn[hh * 4 + 0];
        float4 u1 = Wqn[hh * 4 + 1];
        float4 u2 = Wqn[hh * 4 + 2];
        float4 u3 = Wqn[hh * 4 + 3];
        acc[0]  += o * u0.x; acc[1]  += o * u0.y; acc[2]  += o * u0.z; acc[3]  += o * u0.w;
        acc[4]  += o * u1.x; acc[5]  += o * u1.y; acc[6]  += o * u1.z; acc[7]  += o * u1.w;
        acc[8]  += o * u2.x; acc[9]  += o * u2.y; acc[10] += o * u2.z; acc[11] += o * u2.w;
        acc[12] += o * u3.x; acc[13] += o * u3.y; acc[14] += o * u3.z; acc[15] += o * u3.w;
    }

#pragma unroll
    for (int p = 0; p < 16; ++p)
#pragma unroll
        for (int off = 32; off > 0; off >>= 1)
            acc[p] += __shfl_down(acc[p], off, 64);

    __shared__ float red[4][16];
    int wave = tid >> 6;
    int lane = tid & 63;
    if (lane == 0) {
#pragma unroll
        for (int p = 0; p < 16; ++p) red[wave][p] = acc[p];
    }
    __syncthreads();
    if (tid < 16) {
        float s = red[0][tid] + red[1][tid] + red[2][tid] + red[3][tid] +
                  bq[n * P_DIM + tid];
        qout[n * P_DIM + tid] = s;
    }
}

extern "C" void kernel_launch(void* const* d_in, const int* in_sizes, int n_in,
                              void* d_out, int out_size, void* d_ws, size_t ws_size,
                              hipStream_t stream) {
    const float* x  = (const float*)d_in[0];  // [256,16]
    const int*   ei = (const int*)d_in[1];    // [2,32768]
    const float* W  = (const float*)d_in[2];  // [16,2048]
    const float* b  = (const float*)d_in[3];  // [2048]
    const float* Wq = (const float*)d_in[4];  // [256,2048,16]
    const float* bq = (const float*)d_in[5];  // [256,16]
    float* qout = (float*)d_out;              // [256,16]

    float* ws   = (float*)d_ws;
    float* cntT = ws;                    // 65536 floats (256 KB)
    float* h    = ws + 65536;            // 524288 floats (2 MB)
    float* out  = ws + 65536 + 524288;   // 524288 floats (2 MB)

    hipMemsetAsync(cntT, 0, N_NODES * N_NODES * sizeof(float), stream);
    k_edges_h<<<2176, 256, 0, stream>>>(ei, cntT, x, W, h);
    dim3 g2(16, 16);
    k_out<<<g2, 256, 0, stream>>>(cntT, h, b, out);
    k_q<<<256, 256, 0, stream>>>(out, Wq, bq, qout);
}